// Round 4
// baseline (181.594 us; speedup 1.0000x reference)
//
#include <hip/hip_runtime.h>

typedef __bf16 bf16;
typedef __bf16 bf16x8 __attribute__((ext_vector_type(8)));
typedef __bf16 bf16x4 __attribute__((ext_vector_type(4)));
typedef float f32x4 __attribute__((ext_vector_type(4)));

// x: [256][4096] f32, conv_w: [1536][256] f32, out: [512][4096] f32
// heads=8; channels per head: key [0:64), query [64:128), value [128:192)
// qkvT per head (786432): [QT(query) [4096][64] | KT(key) [4096][64] | V [64][4096]]
// k_conv stores RAW (pre-norm) bf16. k_normqk applies affine to Q/K in place
// (query gets log2(e)/8 folded in). V's affine folds into k_final exactly:
// out = a_v * (sum_s O_s)/(sum_s L_s) + b_v   (since sum_l P = L).

// ---------------- K_misc: xpose + cast_w + zero(cs) ----------------
__global__ void k_misc(const float* __restrict__ x, const float* __restrict__ w,
                       bf16* __restrict__ xT, bf16* __restrict__ wb, float* __restrict__ cs) {
    int b = blockIdx.x;
    if (b < 512) {
        int t = b * 256 + threadIdx.x;
        int p  = t & 4095;
        int c0 = (t >> 12) * 8;
        bf16x8 o;
#pragma unroll
        for (int j = 0; j < 8; j++) o[j] = (bf16)x[(c0 + j) * 4096 + p];
        *(bf16x8*)(xT + p * 256 + c0) = o;
    } else if (b < 896) {
        int idx = ((b - 512) * 256 + threadIdx.x) * 4;
        float4 f = *(const float4*)(w + idx);
        bf16x4 o;
        o[0] = (bf16)f.x; o[1] = (bf16)f.y; o[2] = (bf16)f.z; o[3] = (bf16)f.w;
        *(bf16x4*)(wb + idx) = o;
    } else {
#pragma unroll
        for (int i = 0; i < 12; i++) cs[i * 256 + threadIdx.x] = 0.f;
    }
}

// ---------------- K1: conv GEMM -> stats + LDS-transposed coalesced stores ----------------
__global__ __launch_bounds__(256) void k_conv(const bf16* __restrict__ Wb,
                                              const bf16* __restrict__ xT,
                                              bf16* __restrict__ qkvT,
                                              float* __restrict__ cs) {
    __shared__ __attribute__((aligned(16))) bf16 tile[64 * 72];
    int wid = threadIdx.x >> 6, lane = threadIdx.x & 63;
    int quad = lane >> 4, l15 = lane & 15;
    int g  = blockIdx.x % 24;
    int pb = (blockIdx.x / 24) * 64;
    int h = g / 3, sec = g % 3;          // 0=key 1=query 2=value
    int ob = g * 64;
    int orow = ob + wid * 16 + l15;

    f32x4 acc[4];
#pragma unroll
    for (int c = 0; c < 4; c++) acc[c] = (f32x4){0.f, 0.f, 0.f, 0.f};

#pragma unroll
    for (int ks = 0; ks < 8; ks++) {
        bf16x8 a = *(const bf16x8*)(Wb + orow * 256 + ks * 32 + quad * 8);
#pragma unroll
        for (int c = 0; c < 4; c++) {
            bf16x8 b = *(const bf16x8*)(xT + (pb + c * 16 + l15) * 256 + ks * 32 + quad * 8);
            acc[c] = __builtin_amdgcn_mfma_f32_16x16x32_bf16(a, b, acc[c], 0, 0, 0);
        }
    }

    // per-channel partial stats (f32 accuracy), atomics
    int ch0 = wid * 16 + quad * 4;       // local channel base of this lane's rows
#pragma unroll
    for (int r = 0; r < 4; r++) {
        float sp  = acc[0][r] + acc[1][r] + acc[2][r] + acc[3][r];
        float ssp = acc[0][r] * acc[0][r] + acc[1][r] * acc[1][r]
                  + acc[2][r] * acc[2][r] + acc[3][r] * acc[3][r];
#pragma unroll
        for (int m = 1; m < 16; m <<= 1) {
            sp  += __shfl_xor(sp,  m, 64);
            ssp += __shfl_xor(ssp, m, 64);
        }
        if (l15 == 0) {
            atomicAdd(cs + (ob + ch0 + r) * 2,     sp);
            atomicAdd(cs + (ob + ch0 + r) * 2 + 1, ssp);
        }
    }

    // stage C-tile in LDS (layout depends on destination), then coalesced store
    if (sec == 2) {                      // V wants [ch][px]
#pragma unroll
        for (int c = 0; c < 4; c++)
#pragma unroll
            for (int r = 0; r < 4; r++)
                tile[(ch0 + r) * 72 + c * 16 + l15] = (bf16)acc[c][r];
    } else {                             // Q/K want [px][ch]
#pragma unroll
        for (int c = 0; c < 4; c++) {
            bf16x4 o;
#pragma unroll
            for (int r = 0; r < 4; r++) o[r] = (bf16)acc[c][r];
            *(bf16x4*)(&tile[(c * 16 + l15) * 72 + ch0]) = o;
        }
    }
    __syncthreads();
    bf16* base = qkvT + h * 786432;
    int t = threadIdx.x;
    if (sec == 2) {
        bf16* V = base + 524288;
#pragma unroll
        for (int it = 0; it < 2; it++) {
            int e = it * 256 + t; int ch = e >> 3; int pxo = (e & 7) * 8;
            *(bf16x8*)(V + ch * 4096 + pb + pxo) = *(const bf16x8*)(&tile[ch * 72 + pxo]);
        }
    } else {
        bf16* dst = base + (sec == 0 ? 262144 : 0);
#pragma unroll
        for (int it = 0; it < 2; it++) {
            int e = it * 256 + t; int px = e >> 3; int cho = (e & 7) * 8;
            *(bf16x8*)(dst + (pb + px) * 64 + cho) = *(const bf16x8*)(&tile[px * 72 + cho]);
        }
    }
}

// ---------------- K2: group stats -> per-channel affine (a,b) ----------------
__global__ void k_stats(const float2* __restrict__ cs, const float* __restrict__ gnw,
                        const float* __restrict__ gnb, float2* __restrict__ ab) {
    int g = blockIdx.x, t = threadIdx.x;   // 24 x 64
    float2 v = cs[g * 64 + t];
    float s = v.x, ss = v.y;
#pragma unroll
    for (int m = 1; m < 64; m <<= 1) { s += __shfl_xor(s, m, 64); ss += __shfl_xor(ss, m, 64); }
    const float N = 64.0f * 4096.0f;
    float mean = s / N;
    float inv  = rsqrtf(ss / N - mean * mean + 1e-5f);
    float f = (g % 3 == 1) ? 0.18033688011112042f : 1.0f;   // log2(e)/8 into query
    int ch = g * 64 + t;
    float a = inv * gnw[ch] * f;
    float b = (gnb[ch] - mean * inv * gnw[ch]) * f;
    ab[ch] = make_float2(a, b);
}

// ---------------- K3: in-place affine on Q/K halves only ----------------
__global__ __launch_bounds__(256) void k_normqk(bf16* __restrict__ qkv,
                                                const float2* __restrict__ ab) {
    int h = blockIdx.x >> 8;
    int e = ((blockIdx.x & 255) * 256 + threadIdx.x) * 8;   // 0..524287
    bf16* p = qkv + h * 786432 + e;
    int cb = h * 192 + ((e < 262144) ? 64 : 0) + (e & 63);  // QT=query, KT=key
    bf16x8 v = *(bf16x8*)p;
    bf16x8 o;
#pragma unroll
    for (int j = 0; j < 8; j++) {
        float2 sv = ab[cb + j];
        o[j] = (bf16)(sv.x * (float)v[j] + sv.y);
    }
    *(bf16x8*)p = o;
}

// ---------------- K4: flash attention, 256q WG, 6-way L split, halved Ps ----------------
__global__ __launch_bounds__(256, 2) void k_attn(const bf16* __restrict__ qkvT,
                                                 bf16* __restrict__ Opart,
                                                 float* __restrict__ Lsum) {
    int bid   = blockIdx.x;               // 768 = 8h x 16qb x 6split
    int h     = bid & 7;
    int qb    = (bid >> 3) & 15;
    int split = bid >> 7;                 // 0..5
    int wid = threadIdx.x >> 6, lane = threadIdx.x & 63;
    int quad = lane >> 4, l15 = lane & 15;
    const bf16* QT = qkvT + h * 786432;
    const bf16* KT = QT + 262144;
    const bf16* V  = QT + 524288;
    int qw = qb * 256 + wid * 64;

    __shared__ __attribute__((aligned(16))) bf16 Ks[64 * 72];
    __shared__ __attribute__((aligned(16))) bf16 Vs[64 * 72];
    __shared__ __attribute__((aligned(16))) bf16 Ps[4][32 * 72];   // 2 q-subtiles at a time

    bf16x8 bq[4][2];
#pragma unroll
    for (int qs = 0; qs < 4; qs++)
#pragma unroll
        for (int ks = 0; ks < 2; ks++)
            bq[qs][ks] = *(const bf16x8*)(QT + (qw + qs * 16 + l15) * 64 + ks * 32 + quad * 8);

    f32x4 oacc[4][4];
#pragma unroll
    for (int c = 0; c < 4; c++)
#pragma unroll
        for (int qs = 0; qs < 4; qs++) oacc[c][qs] = (f32x4){0.f, 0.f, 0.f, 0.f};
    float ls[4] = {0.f, 0.f, 0.f, 0.f};

    int t0 = (split * 64) / 6, t1 = ((split + 1) * 64) / 6;
    for (int lt = t0; lt < t1; lt++) {
        int lbase = lt * 64;
        __syncthreads();
#pragma unroll
        for (int rep = 0; rep < 2; rep++) {
            int ck = rep * 256 + threadIdx.x;
            int r = ck >> 3; int off = (ck & 7) * 8;
            *(bf16x8*)(Ks + r * 72 + off) = *(const bf16x8*)(KT + (lbase + r) * 64 + off);
            *(bf16x8*)(Vs + r * 72 + off) = *(const bf16x8*)(V + r * 4096 + lbase + off);
        }
        __syncthreads();

        bf16x8 ak[2][4];
#pragma unroll
        for (int ks = 0; ks < 2; ks++)
#pragma unroll
            for (int lb = 0; lb < 4; lb++)
                ak[ks][lb] = *(const bf16x8*)(Ks + (lb * 16 + l15) * 72 + ks * 32 + quad * 8);
        bf16x8 av[2][4];
#pragma unroll
        for (int ks = 0; ks < 2; ks++)
#pragma unroll
            for (int c = 0; c < 4; c++)
                av[ks][c] = *(const bf16x8*)(Vs + (c * 16 + l15) * 72 + ks * 32 + quad * 8);

#pragma unroll
        for (int qp = 0; qp < 2; qp++) {
            // S^T = K·Q and P = exp2 for 2 q-subtiles into the halved Ps
#pragma unroll
            for (int q2 = 0; q2 < 2; q2++) {
                int qs = qp * 2 + q2;
                f32x4 s[4];
#pragma unroll
                for (int lb = 0; lb < 4; lb++) s[lb] = (f32x4){0.f, 0.f, 0.f, 0.f};
#pragma unroll
                for (int ks = 0; ks < 2; ks++)
#pragma unroll
                    for (int lb = 0; lb < 4; lb++)
                        s[lb] = __builtin_amdgcn_mfma_f32_16x16x32_bf16(ak[ks][lb], bq[qs][ks], s[lb], 0, 0, 0);
#pragma unroll
                for (int lb = 0; lb < 4; lb++) {
                    float p0 = exp2f(s[lb][0]);
                    float p1 = exp2f(s[lb][1]);
                    float p2 = exp2f(s[lb][2]);
                    float p3 = exp2f(s[lb][3]);
                    ls[qs] += (p0 + p1) + (p2 + p3);
                    bf16x4 pk;
                    pk[0] = (bf16)p0; pk[1] = (bf16)p1; pk[2] = (bf16)p2; pk[3] = (bf16)p3;
                    *(bf16x4*)(&Ps[wid][(q2 * 16 + l15) * 72 + lb * 16 + quad * 4]) = pk;
                }
            }
            // O += V·P for the same 2 q-subtiles (Ps per-wave private: no barrier)
#pragma unroll
            for (int q2 = 0; q2 < 2; q2++) {
                int qs = qp * 2 + q2;
                bf16x8 bp0 = *(const bf16x8*)(&Ps[wid][(q2 * 16 + l15) * 72 + quad * 8]);
                bf16x8 bp1 = *(const bf16x8*)(&Ps[wid][(q2 * 16 + l15) * 72 + 32 + quad * 8]);
#pragma unroll
                for (int c = 0; c < 4; c++) {
                    oacc[c][qs] = __builtin_amdgcn_mfma_f32_16x16x32_bf16(av[0][c], bp0, oacc[c][qs], 0, 0, 0);
                    oacc[c][qs] = __builtin_amdgcn_mfma_f32_16x16x32_bf16(av[1][c], bp1, oacc[c][qs], 0, 0, 0);
                }
            }
        }
    }

#pragma unroll
    for (int qs = 0; qs < 4; qs++) {
        float l = ls[qs];
        l += __shfl_xor(l, 16, 64);
        l += __shfl_xor(l, 32, 64);
        if (quad == 0)
            Lsum[split * 32768 + h * 4096 + qw + qs * 16 + l15] = l;
    }

    bf16* Ob = Opart + split * 2097152;
#pragma unroll
    for (int c = 0; c < 4; c++)
#pragma unroll
        for (int qs = 0; qs < 4; qs++)
#pragma unroll
            for (int r = 0; r < 4; r++)
                Ob[(h * 64 + c * 16 + quad * 4 + r) * 4096 + qw + qs * 16 + l15] = (bf16)oacc[c][qs][r];
}

// ---------------- K5: combine 6 splits + V affine + normalize ----------------
__global__ void k_final(const bf16* __restrict__ Opart, const float* __restrict__ Lsum,
                        const float2* __restrict__ ab, float* __restrict__ out) {
    int gid = blockIdx.x * 256 + threadIdx.x;    // 262144
    int row = gid >> 9;
    int c8  = (gid & 511) << 3;
    int h   = row >> 6;
    float2 vab = ab[h * 192 + 128 + (row & 63)];
    float o[8] = {0, 0, 0, 0, 0, 0, 0, 0};
    float l[8] = {0, 0, 0, 0, 0, 0, 0, 0};
#pragma unroll
    for (int s = 0; s < 6; s++) {
        bf16x8 v = *(const bf16x8*)(Opart + s * 2097152 + row * 4096 + c8);
        const float* L = Lsum + s * 32768 + h * 4096 + c8;
        float4 l0 = *(const float4*)L;
        float4 l1 = *(const float4*)(L + 4);
#pragma unroll
        for (int j = 0; j < 8; j++) o[j] += (float)v[j];
        l[0] += l0.x; l[1] += l0.y; l[2] += l0.z; l[3] += l0.w;
        l[4] += l1.x; l[5] += l1.y; l[6] += l1.z; l[7] += l1.w;
    }
    float4 r0, r1;
    r0.x = vab.x * o[0] / l[0] + vab.y; r0.y = vab.x * o[1] / l[1] + vab.y;
    r0.z = vab.x * o[2] / l[2] + vab.y; r0.w = vab.x * o[3] / l[3] + vab.y;
    r1.x = vab.x * o[4] / l[4] + vab.y; r1.y = vab.x * o[5] / l[5] + vab.y;
    r1.z = vab.x * o[6] / l[6] + vab.y; r1.w = vab.x * o[7] / l[7] + vab.y;
    *(float4*)(out + row * 4096 + c8)     = r0;
    *(float4*)(out + row * 4096 + c8 + 4) = r1;
}

extern "C" void kernel_launch(void* const* d_in, const int* in_sizes, int n_in,
                              void* d_out, int out_size, void* d_ws, size_t ws_size,
                              hipStream_t stream) {
    const float* x      = (const float*)d_in[0];
    const float* conv_w = (const float*)d_in[1];
    const float* gn_w   = (const float*)d_in[2];
    const float* gn_b   = (const float*)d_in[3];
    float* out = (float*)d_out;
    char* ws = (char*)d_ws;

    // Layout (total 36.8 MB). Wb/xT alias the front of Opart: they are dead
    // after k_conv; Opart is first written by k_attn (after k_normqk).
    bf16*   qkvT  = (bf16*) (ws);                   // [0, 12582912)
    bf16*   Opart = (bf16*) (ws + 12582912);        // [12582912, 37748736) 6x4MB
    bf16*   Wb    = (bf16*) (ws + 12582912);        // alias (dead after k_conv)
    bf16*   xT    = (bf16*) (ws + 13369344);        // alias (dead after k_conv)
    float*  Lsum  = (float*)(ws + 37748736);        // 6x131072 B
    float*  cs    = (float*)(ws + 38535168);        // 12288 B
    float2* ab    = (float2*)(ws + 38547456);       // 12288 B

    hipLaunchKernelGGL(k_misc,   dim3(897),  dim3(256), 0, stream, x, conv_w, xT, Wb, cs);
    hipLaunchKernelGGL(k_conv,   dim3(1536), dim3(256), 0, stream, Wb, xT, qkvT, cs);
    hipLaunchKernelGGL(k_stats,  dim3(24),   dim3(64),  0, stream, (const float2*)cs, gn_w, gn_b, ab);
    hipLaunchKernelGGL(k_normqk, dim3(2048), dim3(256), 0, stream, qkvT, (const float2*)ab);
    hipLaunchKernelGGL(k_attn,   dim3(768),  dim3(256), 0, stream, qkvT, Opart, Lsum);
    hipLaunchKernelGGL(k_final,  dim3(1024), dim3(256), 0, stream, Opart, Lsum, (const float2*)ab, out);
}